// Round 3
// baseline (84546.320 us; speedup 1.0000x reference)
//
#include <hip/hip_runtime.h>
#include <hip/hip_bf16.h>

#define HIDN 1024
#define LATD 128
#define INPD 512
#define BATCH 128
#define NG 4096   // 4*HIDN
#define NWG 512

typedef unsigned short u16;
typedef __attribute__((ext_vector_type(8))) short s16x8;
typedef __attribute__((ext_vector_type(4))) float f32x4;

__device__ __forceinline__ u16 f2bf(float f) {
    union { float f; unsigned u; } x;
    x.f = f;
    unsigned r = x.u + 0x7fffu + ((x.u >> 16) & 1u);
    return (u16)(r >> 16);
}
__device__ __forceinline__ float sigm(float x) {
    return 1.f / (1.f + __expf(-x));
}
__device__ __forceinline__ f32x4 shflx(f32x4 v, int m) {
    f32x4 r;
    r[0] = __shfl_xor(v[0], m);
    r[1] = __shfl_xor(v[1], m);
    r[2] = __shfl_xor(v[2], m);
    r[3] = __shfl_xor(v[3], m);
    return r;
}

// device-wide barrier: all NWG workgroups co-resident (LDS-capacity guaranteed)
__device__ __forceinline__ void gbar(unsigned* bar, unsigned target) {
    __syncthreads();
    if (threadIdx.x == 0) {
        __hip_atomic_fetch_add(bar, 1u, __ATOMIC_RELEASE, __HIP_MEMORY_SCOPE_AGENT);
        while (__hip_atomic_load(bar, __ATOMIC_ACQUIRE, __HIP_MEMORY_SCOPE_AGENT) < target)
            __builtin_amdgcn_s_sleep(8);
    }
    __syncthreads();
}

// ---------------------------------------------------------------------------
// f32 -> bf16 conversion, 4 elements/thread
// ---------------------------------------------------------------------------
__global__ __launch_bounds__(256) void k_cvt(
    const float* __restrict__ src, u16* __restrict__ dst, int n4)
{
    int i = blockIdx.x * 256 + threadIdx.x;
    if (i < n4) {
        float4 v = ((const float4*)src)[i];
        ushort4 o;
        o.x = f2bf(v.x); o.y = f2bf(v.y); o.z = f2bf(v.z); o.w = f2bf(v.w);
        ((ushort4*)dst)[i] = o;
    }
}

// ---------------------------------------------------------------------------
// init: dh = latent @ W_fc.T + b_fc -> scatter into h[0][l][b][k], c[l][b][k]
// dh element (m, n): l = m>>6 ; bb = 2*(m&63) + (n>>11) ; k2 = n&2047
// ---------------------------------------------------------------------------
__global__ __launch_bounds__(256) void k_init(
    const u16* __restrict__ latent, const u16* __restrict__ Wfc,
    const float* __restrict__ bfc,
    u16* __restrict__ h_bf,      // [2 parity][2 layer][B][HIDN]; writes parity 0
    u16* __restrict__ c_bf,      // [2][B][HIDN]
    float* __restrict__ c_f32)   // [2][B][HIDN]
{
    int tid = threadIdx.x, lane = tid & 63, w = tid >> 6;
    int blk = blockIdx.x;              // mt*64 + ngi
    int mt = blk >> 6, ngi = blk & 63;
    int nt = ngi * 4 + w;              // 0..255
    int arow = mt * 16 + (lane & 15);
    int ak = (lane >> 4) * 8;
    int bn = nt * 16 + (lane & 15);
    const u16* xp = latent + (size_t)arow * LATD + ak;
    const u16* wp = Wfc + (size_t)bn * LATD + ak;
    f32x4 acc = {0.f, 0.f, 0.f, 0.f};
#pragma unroll
    for (int kk = 0; kk < LATD; kk += 32) {
        s16x8 a = *(const s16x8*)(xp + kk);
        s16x8 b = *(const s16x8*)(wp + kk);
        acc = __builtin_amdgcn_mfma_f32_16x16x32_bf16(a, b, acc, 0, 0, 0);
    }
    int col = lane & 15, rbase = (lane >> 4) * 4;
    int n = nt * 16 + col;
    float bias = bfc[n];
#pragma unroll
    for (int r = 0; r < 4; ++r) {
        int m = mt * 16 + rbase + r;
        float v = acc[r] + bias;
        int ll = m >> 6;
        int bb = 2 * (m & 63) + (n >> 11);
        int k2 = n & 2047;
        size_t base = ((size_t)(ll * BATCH + bb)) << 10;
        if (k2 < 1024) {
            h_bf[base + k2] = f2bf(v);
        } else {
            int kq = k2 - 1024;
            c_f32[base + kq] = v;
            c_bf[base + kq] = f2bf(v);
        }
    }
}

// ---------------------------------------------------------------------------
// cell phase body (inlined): gates = X @ Wih.T + hc @ Whh.T + bi + bh,
// weights already in LDS (16 rows x RB bytes, XOR-swizzled), then pointwise.
// N-tile col c -> n = (c>>2)*1024 + j0 + (c&3)  (gate-major, 4 j per WG)
// ---------------------------------------------------------------------------
__device__ __forceinline__ void cellp(
    const u16* smem, int RB,
    const u16* __restrict__ X, int xstr, int nXks,
    const u16* __restrict__ hc, int kbH,
    const float* __restrict__ bi, const float* __restrict__ bh,
    float* __restrict__ cf, u16* __restrict__ cb, u16* __restrict__ hn,
    int j0)
{
    int tid = threadIdx.x, lane = tid & 63, w = tid >> 6;
    int c = lane & 15, q = lane >> 4;
    int sw = (c & 7) << 4;
    int mt0 = 2 * w, mt1 = 2 * w + 1;
    const char* brow = (const char*)smem + c * RB;
    const u16* ax0 = X + (size_t)(mt0 * 16 + c) * xstr + q * 8;
    const u16* ax1 = X + (size_t)(mt1 * 16 + c) * xstr + q * 8;
    f32x4 acc0 = {0.f, 0.f, 0.f, 0.f}, acc1 = {0.f, 0.f, 0.f, 0.f};
#pragma unroll 4
    for (int ks = 0; ks < nXks; ++ks) {
        int kb = ks * 64 + q * 16;
        s16x8 b = *(const s16x8*)(brow + (kb ^ sw));
        s16x8 a0 = *(const s16x8*)(ax0 + ks * 32);
        s16x8 a1 = *(const s16x8*)(ax1 + ks * 32);
        acc0 = __builtin_amdgcn_mfma_f32_16x16x32_bf16(a0, b, acc0, 0, 0, 0);
        acc1 = __builtin_amdgcn_mfma_f32_16x16x32_bf16(a1, b, acc1, 0, 0, 0);
    }
    const u16* ah0 = hc + (size_t)(mt0 * 16 + c) * HIDN + q * 8;
    const u16* ah1 = hc + (size_t)(mt1 * 16 + c) * HIDN + q * 8;
#pragma unroll 4
    for (int ks = 0; ks < 32; ++ks) {
        int kb = kbH + ks * 64 + q * 16;
        s16x8 b = *(const s16x8*)(brow + (kb ^ sw));
        s16x8 a0 = *(const s16x8*)(ah0 + ks * 32);
        s16x8 a1 = *(const s16x8*)(ah1 + ks * 32);
        acc0 = __builtin_amdgcn_mfma_f32_16x16x32_bf16(a0, b, acc0, 0, 0, 0);
        acc1 = __builtin_amdgcn_mfma_f32_16x16x32_bf16(a1, b, acc1, 0, 0, 0);
    }
    int n = (c >> 2) * 1024 + j0 + (c & 3);
    float bsum = bi[n] + bh[n];
#pragma unroll
    for (int r = 0; r < 4; ++r) { acc0[r] += bsum; acc1[r] += bsum; }
    f32x4 f0 = shflx(acc0, 4), g0 = shflx(acc0, 8), o0 = shflx(acc0, 12);
    f32x4 f1 = shflx(acc1, 4), g1 = shflx(acc1, 8), o1 = shflx(acc1, 12);
    if (c < 4) {
        int j = j0 + c;
#pragma unroll
        for (int r = 0; r < 4; ++r) {
            int b = mt0 * 16 + q * 4 + r;
            size_t idx = (size_t)b * HIDN + j;
            float cp = cf[idx];
            float iv = sigm(acc0[r]), fv = sigm(f0[r]);
            float gv = tanhf(g0[r]), ov = sigm(o0[r]);
            float c2 = fv * cp + iv * gv;
            float h2 = ov * tanhf(c2);
            cf[idx] = c2; cb[idx] = f2bf(c2); hn[idx] = f2bf(h2);
        }
#pragma unroll
        for (int r = 0; r < 4; ++r) {
            int b = mt1 * 16 + q * 4 + r;
            size_t idx = (size_t)b * HIDN + j;
            float cp = cf[idx];
            float iv = sigm(acc1[r]), fv = sigm(f1[r]);
            float gv = tanhf(g1[r]), ov = sigm(o1[r]);
            float c2 = fv * cp + iv * gv;
            float h2 = ov * tanhf(c2);
            cf[idx] = c2; cb[idx] = f2bf(c2); hn[idx] = f2bf(h2);
        }
    }
}

// ---------------------------------------------------------------------------
// persistent kernel: 512 WGs (A: wg<256 -> map + cell0 ; B: -> cell1)
// ---------------------------------------------------------------------------
__global__ __launch_bounds__(256, 2) void k_persist(
    const u16* __restrict__ wmap, const float* __restrict__ bmap,
    const float* __restrict__ bih0, const float* __restrict__ bhh0,
    const float* __restrict__ bih1, const float* __restrict__ bhh1,
    const u16* __restrict__ wih0, const u16* __restrict__ whh0,
    const u16* __restrict__ wih1, const u16* __restrict__ whh1,
    u16* __restrict__ h_bf,   // [2 parity][2 layer][B][H]
    u16* __restrict__ c_bf,   // [2 layer][B][H]
    float* __restrict__ c_f32,
    u16* __restrict__ out_bf, // [B][INPD]
    float* __restrict__ out,  // [seq][B][INPD]
    int seq, unsigned* bar)
{
    __shared__ u16 smem[32768];   // 64 KB
    const int wg = blockIdx.x;
    const bool isA = wg < 256;
    const int tid = threadIdx.x;
    const int lane = tid & 63;
    const int w = tid >> 6;
    const int c = lane & 15, q = lane >> 4;
    const size_t LBH = (size_t)BATCH * HIDN;

    // ---- prologue: stage this WG's weight slice into LDS (XOR-swizzled) ----
    {
        int tr = tid >> 4, sub = tid & 15;
        if (isA) {
            int n = (tr >> 2) * 1024 + wg * 4 + (tr & 3);
#pragma unroll
            for (int it = 0; it < 12; ++it) {
                int kb = (sub + 16 * it) * 16;
                const u16* src = (kb < 1024) ? (wih0 + (size_t)n * 512 + (kb >> 1))
                                             : (whh0 + (size_t)n * 1024 + ((kb - 1024) >> 1));
                *(s16x8*)((char*)smem + tr * 3072 + (kb ^ ((tr & 7) << 4))) =
                    *(const s16x8*)src;
            }
        } else {
            int n = (tr >> 2) * 1024 + (wg - 256) * 4 + (tr & 3);
#pragma unroll
            for (int it = 0; it < 16; ++it) {
                int kb = (sub + 16 * it) * 16;
                const u16* src = (kb < 2048) ? (wih1 + (size_t)n * 1024 + (kb >> 1))
                                             : (whh1 + (size_t)n * 1024 + ((kb - 2048) >> 1));
                *(s16x8*)((char*)smem + tr * 4096 + (kb ^ ((tr & 7) << 4))) =
                    *(const s16x8*)src;
            }
        }
    }
    __syncthreads();

    unsigned epoch = 0;
    for (int t = 0; t < seq; ++t) {
        int p = t & 1;
        const u16* h0c = h_bf + ((size_t)(p * 2 + 0)) * LBH;
        const u16* h1c = h_bf + ((size_t)(p * 2 + 1)) * LBH;
        u16* h0n = h_bf + ((size_t)((p ^ 1) * 2 + 0)) * LBH;
        u16* h1n = h_bf + ((size_t)((p ^ 1) * 2 + 1)) * LBH;

        // ---------- phase M: out_t = sigmoid(fc_in @ Wmap.T + bmap) ----------
        if (isA) {
            int ct = wg & 31, mt = wg >> 5;       // N-tile, M-tile
            int l = mt >> 2;                       // layer for these rows
            int i = mt * 16 + c;                   // fc_in row
            int b0 = 2 * (i & 63);
            int bsel = b0 + (w >> 1);              // wave w <-> segment w
            const u16* segbase = ((w & 1) == 0)
                ? (h_bf + ((size_t)(p * 2 + l) * BATCH + bsel) * HIDN)
                : (c_bf + ((size_t)l * BATCH + bsel) * HIDN);
            const u16* ap = segbase + q * 8;
            const u16* wp = wmap + ((size_t)(16 * ct + c)) * NG + w * 1024 + q * 8;
            f32x4 acc = {0.f, 0.f, 0.f, 0.f};
#pragma unroll 4
            for (int ks = 0; ks < 32; ++ks) {
                s16x8 a = *(const s16x8*)(ap + ks * 32);
                s16x8 b = *(const s16x8*)(wp + ks * 32);
                acc = __builtin_amdgcn_mfma_f32_16x16x32_bf16(a, b, acc, 0, 0, 0);
            }
            float* sc = (float*)((char*)smem + 49152);
#pragma unroll
            for (int r = 0; r < 4; ++r) sc[w * 256 + (q * 4 + r) * 16 + c] = acc[r];
            __syncthreads();
            {
                int row = tid >> 4, cl = tid & 15;
                float v = sc[row * 16 + cl] + sc[256 + row * 16 + cl]
                        + sc[512 + row * 16 + cl] + sc[768 + row * 16 + cl];
                int n = 16 * ct + cl;
                v = sigm(v + bmap[n]);
                int b = mt * 16 + row;
                out[((size_t)t * BATCH + b) * INPD + n] = v;
                out_bf[b * INPD + n] = f2bf(v);
            }
        }
        gbar(bar, ++epoch * NWG);

        if (t < seq - 1) {
            // ---------- phase C0 (A-class) ----------
            if (isA) {
                cellp(smem, 3072, out_bf, INPD, 16, h0c, 1024,
                      bih0, bhh0, c_f32, c_bf, h0n, wg * 4);
            }
            gbar(bar, ++epoch * NWG);
            // ---------- phase C1 (B-class) ----------
            if (!isA) {
                cellp(smem, 4096, h0n, HIDN, 32, h1c, 2048,
                      bih1, bhh1, c_f32 + LBH, c_bf + LBH, h1n, (wg - 256) * 4);
            }
            gbar(bar, ++epoch * NWG);
        } else {
            gbar(bar, ++epoch * NWG);
            gbar(bar, ++epoch * NWG);
        }
    }
}

extern "C" void kernel_launch(void* const* d_in, const int* in_sizes, int n_in,
                              void* d_out, int out_size, void* d_ws, size_t ws_size,
                              hipStream_t stream)
{
    const float* latent = (const float*)d_in[0];
    const float* Wfc  = (const float*)d_in[2];
    const float* bfc  = (const float*)d_in[3];
    const float* Wmap = (const float*)d_in[4];
    const float* bmap = (const float*)d_in[5];
    const float* Wih0 = (const float*)d_in[6];
    const float* Whh0 = (const float*)d_in[7];
    const float* bih0 = (const float*)d_in[8];
    const float* bhh0 = (const float*)d_in[9];
    const float* Wih1 = (const float*)d_in[10];
    const float* Whh1 = (const float*)d_in[11];
    const float* bih1 = (const float*)d_in[12];
    const float* bhh1 = (const float*)d_in[13];
    float* out = (float*)d_out;
    int seq = out_size / (BATCH * INPD);

    const size_t N_LAT = (size_t)BATCH * LATD;
    const size_t N_FC  = (size_t)NG * LATD;
    const size_t N_MAP = (size_t)INPD * NG;
    const size_t N_IH0 = (size_t)NG * INPD;
    const size_t N_HH  = (size_t)NG * HIDN;
    const size_t LBH   = (size_t)BATCH * HIDN;

    u16* p = (u16*)d_ws;
    u16* wbf_lat = p; p += N_LAT;
    u16* wbf_fc  = p; p += N_FC;
    u16* wbf_map = p; p += N_MAP;
    u16* wbf_ih0 = p; p += N_IH0;
    u16* wbf_hh0 = p; p += N_HH;
    u16* wbf_ih1 = p; p += N_HH;
    u16* wbf_hh1 = p; p += N_HH;
    u16* h_bf    = p; p += 4 * LBH;   // [2 parity][2 layer][B][H]
    u16* c_bf    = p; p += 2 * LBH;
    u16* out_bf  = p; p += (size_t)BATCH * INPD;
    float* c_f32 = (float*)p;
    unsigned* bar = (unsigned*)(c_f32 + 2 * LBH);

    hipMemsetAsync((void*)bar, 0, 64, stream);

    {
        struct { const float* s; u16* d; size_t n; } cv[7] = {
            {latent, wbf_lat, N_LAT}, {Wfc, wbf_fc, N_FC}, {Wmap, wbf_map, N_MAP},
            {Wih0, wbf_ih0, N_IH0}, {Whh0, wbf_hh0, N_HH},
            {Wih1, wbf_ih1, N_HH}, {Whh1, wbf_hh1, N_HH}};
        for (int qi = 0; qi < 7; ++qi) {
            int n4 = (int)(cv[qi].n / 4);
            k_cvt<<<(n4 + 255) / 256, 256, 0, stream>>>(cv[qi].s, cv[qi].d, n4);
        }
    }

    k_init<<<512, 256, 0, stream>>>(wbf_lat, wbf_fc, bfc, h_bf, c_bf, c_f32);

    k_persist<<<NWG, 256, 0, stream>>>(
        wbf_map, bmap, bih0, bhh0, bih1, bhh1,
        wbf_ih0, wbf_hh0, wbf_ih1, wbf_hh1,
        h_bf, c_bf, c_f32, out_bf, out, seq, bar);
}

// Round 4
// 38161.417 us; speedup vs baseline: 2.2155x; 2.2155x over previous
//
#include <hip/hip_runtime.h>
#include <hip/hip_bf16.h>

#define HIDN 1024
#define LATD 128
#define INPD 512
#define BATCH 128
#define NG 4096   // 4*HIDN
#define NWG 512

typedef unsigned short u16;
typedef __attribute__((ext_vector_type(8))) short s16x8;
typedef __attribute__((ext_vector_type(4))) float f32x4;

__device__ __forceinline__ u16 f2bf(float f) {
    union { float f; unsigned u; } x;
    x.f = f;
    unsigned r = x.u + 0x7fffu + ((x.u >> 16) & 1u);
    return (u16)(r >> 16);
}
__device__ __forceinline__ float sigm(float x) {
    return 1.f / (1.f + __expf(-x));
}
__device__ __forceinline__ f32x4 shflx(f32x4 v, int m) {
    f32x4 r;
    r[0] = __shfl_xor(v[0], m);
    r[1] = __shfl_xor(v[1], m);
    r[2] = __shfl_xor(v[2], m);
    r[3] = __shfl_xor(v[3], m);
    return r;
}

// device-wide barrier, all NWG workgroups co-resident.
// Release once on arrival; RELAXED polling (no per-iteration L2 invalidate —
// the R3 bug); single agent-acquire fence after the spin exits.
__device__ __forceinline__ void gbar(unsigned* bar, unsigned target) {
    __syncthreads();
    if (threadIdx.x == 0) {
        __hip_atomic_fetch_add(bar, 1u, __ATOMIC_RELEASE, __HIP_MEMORY_SCOPE_AGENT);
        while (__hip_atomic_load(bar, __ATOMIC_RELAXED, __HIP_MEMORY_SCOPE_AGENT) < target)
            __builtin_amdgcn_s_sleep(8);
        __builtin_amdgcn_fence(__ATOMIC_ACQUIRE, "agent");
    }
    __syncthreads();
}

// ---------------------------------------------------------------------------
// f32 -> bf16 conversion, 4 elements/thread
// ---------------------------------------------------------------------------
__global__ __launch_bounds__(256) void k_cvt(
    const float* __restrict__ src, u16* __restrict__ dst, int n4)
{
    int i = blockIdx.x * 256 + threadIdx.x;
    if (i < n4) {
        float4 v = ((const float4*)src)[i];
        ushort4 o;
        o.x = f2bf(v.x); o.y = f2bf(v.y); o.z = f2bf(v.z); o.w = f2bf(v.w);
        ((ushort4*)dst)[i] = o;
    }
}

// ---------------------------------------------------------------------------
// init: dh = latent @ W_fc.T + b_fc -> scatter into h[0][l][b][k], c[l][b][k]
// dh element (m, n): l = m>>6 ; bb = 2*(m&63) + (n>>11) ; k2 = n&2047
// ---------------------------------------------------------------------------
__global__ __launch_bounds__(256) void k_init(
    const u16* __restrict__ latent, const u16* __restrict__ Wfc,
    const float* __restrict__ bfc,
    u16* __restrict__ h_bf,      // [2 parity][2 layer][B][HIDN]; writes parity 0
    u16* __restrict__ c_bf,      // [2][B][HIDN]
    float* __restrict__ c_f32)   // [2][B][HIDN]
{
    int tid = threadIdx.x, lane = tid & 63, w = tid >> 6;
    int blk = blockIdx.x;              // mt*64 + ngi
    int mt = blk >> 6, ngi = blk & 63;
    int nt = ngi * 4 + w;              // 0..255
    int arow = mt * 16 + (lane & 15);
    int ak = (lane >> 4) * 8;
    int bn = nt * 16 + (lane & 15);
    const u16* xp = latent + (size_t)arow * LATD + ak;
    const u16* wp = Wfc + (size_t)bn * LATD + ak;
    f32x4 acc = {0.f, 0.f, 0.f, 0.f};
#pragma unroll
    for (int kk = 0; kk < LATD; kk += 32) {
        s16x8 a = *(const s16x8*)(xp + kk);
        s16x8 b = *(const s16x8*)(wp + kk);
        acc = __builtin_amdgcn_mfma_f32_16x16x32_bf16(a, b, acc, 0, 0, 0);
    }
    int col = lane & 15, rbase = (lane >> 4) * 4;
    int n = nt * 16 + col;
    float bias = bfc[n];
#pragma unroll
    for (int r = 0; r < 4; ++r) {
        int m = mt * 16 + rbase + r;
        float v = acc[r] + bias;
        int ll = m >> 6;
        int bb = 2 * (m & 63) + (n >> 11);
        int k2 = n & 2047;
        size_t base = ((size_t)(ll * BATCH + bb)) << 10;
        if (k2 < 1024) {
            h_bf[base + k2] = f2bf(v);
        } else {
            int kq = k2 - 1024;
            c_f32[base + kq] = v;
            c_bf[base + kq] = f2bf(v);
        }
    }
}

// ---------------------------------------------------------------------------
// cell phase body: gates = X @ Wih.T + hc @ Whh.T + bi + bh,
// weights in LDS (16 rows x RB bytes, XOR-swizzled), then pointwise.
// N-tile col c -> n = (c>>2)*1024 + j0 + (c&3)  (gate-major, 4 j per WG)
// ---------------------------------------------------------------------------
__device__ __forceinline__ void cellp(
    const u16* smem, int RB,
    const u16* __restrict__ X, int xstr, int nXks,
    const u16* __restrict__ hc, int kbH,
    const float* __restrict__ bi, const float* __restrict__ bh,
    float* __restrict__ cf, u16* __restrict__ cb, u16* __restrict__ hn,
    int j0)
{
    int tid = threadIdx.x, lane = tid & 63, w = tid >> 6;
    int c = lane & 15, q = lane >> 4;
    int sw = (c & 7) << 4;
    int mt0 = 2 * w, mt1 = 2 * w + 1;
    const char* brow = (const char*)smem + c * RB;
    const u16* ax0 = X + (size_t)(mt0 * 16 + c) * xstr + q * 8;
    const u16* ax1 = X + (size_t)(mt1 * 16 + c) * xstr + q * 8;
    f32x4 acc0 = {0.f, 0.f, 0.f, 0.f}, acc1 = {0.f, 0.f, 0.f, 0.f};
#pragma unroll 4
    for (int ks = 0; ks < nXks; ++ks) {
        int kb = ks * 64 + q * 16;
        s16x8 b = *(const s16x8*)(brow + (kb ^ sw));
        s16x8 a0 = *(const s16x8*)(ax0 + ks * 32);
        s16x8 a1 = *(const s16x8*)(ax1 + ks * 32);
        acc0 = __builtin_amdgcn_mfma_f32_16x16x32_bf16(a0, b, acc0, 0, 0, 0);
        acc1 = __builtin_amdgcn_mfma_f32_16x16x32_bf16(a1, b, acc1, 0, 0, 0);
    }
    const u16* ah0 = hc + (size_t)(mt0 * 16 + c) * HIDN + q * 8;
    const u16* ah1 = hc + (size_t)(mt1 * 16 + c) * HIDN + q * 8;
#pragma unroll 4
    for (int ks = 0; ks < 32; ++ks) {
        int kb = kbH + ks * 64 + q * 16;
        s16x8 b = *(const s16x8*)(brow + (kb ^ sw));
        s16x8 a0 = *(const s16x8*)(ah0 + ks * 32);
        s16x8 a1 = *(const s16x8*)(ah1 + ks * 32);
        acc0 = __builtin_amdgcn_mfma_f32_16x16x32_bf16(a0, b, acc0, 0, 0, 0);
        acc1 = __builtin_amdgcn_mfma_f32_16x16x32_bf16(a1, b, acc1, 0, 0, 0);
    }
    int n = (c >> 2) * 1024 + j0 + (c & 3);
    float bsum = bi[n] + bh[n];
#pragma unroll
    for (int r = 0; r < 4; ++r) { acc0[r] += bsum; acc1[r] += bsum; }
    f32x4 f0 = shflx(acc0, 4), g0 = shflx(acc0, 8), o0 = shflx(acc0, 12);
    f32x4 f1 = shflx(acc1, 4), g1 = shflx(acc1, 8), o1 = shflx(acc1, 12);
    if (c < 4) {
        int j = j0 + c;
#pragma unroll
        for (int r = 0; r < 4; ++r) {
            int b = mt0 * 16 + q * 4 + r;
            size_t idx = (size_t)b * HIDN + j;
            float cp = cf[idx];
            float iv = sigm(acc0[r]), fv = sigm(f0[r]);
            float gv = tanhf(g0[r]), ov = sigm(o0[r]);
            float c2 = fv * cp + iv * gv;
            float h2 = ov * tanhf(c2);
            cf[idx] = c2; cb[idx] = f2bf(c2); hn[idx] = f2bf(h2);
        }
#pragma unroll
        for (int r = 0; r < 4; ++r) {
            int b = mt1 * 16 + q * 4 + r;
            size_t idx = (size_t)b * HIDN + j;
            float cp = cf[idx];
            float iv = sigm(acc1[r]), fv = sigm(f1[r]);
            float gv = tanhf(g1[r]), ov = sigm(o1[r]);
            float c2 = fv * cp + iv * gv;
            float h2 = ov * tanhf(c2);
            cf[idx] = c2; cb[idx] = f2bf(c2); hn[idx] = f2bf(h2);
        }
    }
}

// ---------------------------------------------------------------------------
// persistent kernel: 512 WGs (A: wg<256 -> map + cell0 ; B: -> cell1)
// ---------------------------------------------------------------------------
__global__ __launch_bounds__(256, 2) void k_persist(
    const u16* __restrict__ wmap, const float* __restrict__ bmap,
    const float* __restrict__ bih0, const float* __restrict__ bhh0,
    const float* __restrict__ bih1, const float* __restrict__ bhh1,
    const u16* __restrict__ wih0, const u16* __restrict__ whh0,
    const u16* __restrict__ wih1, const u16* __restrict__ whh1,
    u16* __restrict__ h_bf,   // [2 parity][2 layer][B][H]
    u16* __restrict__ c_bf,   // [2 layer][B][H]
    float* __restrict__ c_f32,
    u16* __restrict__ out_bf, // [B][INPD]
    float* __restrict__ out,  // [seq][B][INPD]
    int seq, unsigned* bar)
{
    __shared__ u16 smem[32768];   // 64 KB
    const int wg = blockIdx.x;
    const bool isA = wg < 256;
    const int tid = threadIdx.x;
    const int lane = tid & 63;
    const int w = tid >> 6;
    const int c = lane & 15, q = lane >> 4;
    const size_t LBH = (size_t)BATCH * HIDN;

    // ---- prologue: stage this WG's weight slice into LDS (XOR-swizzled) ----
    {
        int tr = tid >> 4, sub = tid & 15;
        if (isA) {
            int n = (tr >> 2) * 1024 + wg * 4 + (tr & 3);
#pragma unroll
            for (int it = 0; it < 12; ++it) {
                int kb = (sub + 16 * it) * 16;
                const u16* src = (kb < 1024) ? (wih0 + (size_t)n * 512 + (kb >> 1))
                                             : (whh0 + (size_t)n * 1024 + ((kb - 1024) >> 1));
                *(s16x8*)((char*)smem + tr * 3072 + (kb ^ ((tr & 7) << 4))) =
                    *(const s16x8*)src;
            }
        } else {
            int n = (tr >> 2) * 1024 + (wg - 256) * 4 + (tr & 3);
#pragma unroll
            for (int it = 0; it < 16; ++it) {
                int kb = (sub + 16 * it) * 16;
                const u16* src = (kb < 2048) ? (wih1 + (size_t)n * 1024 + (kb >> 1))
                                             : (whh1 + (size_t)n * 1024 + ((kb - 2048) >> 1));
                *(s16x8*)((char*)smem + tr * 4096 + (kb ^ ((tr & 7) << 4))) =
                    *(const s16x8*)src;
            }
        }
    }
    __syncthreads();

    unsigned epoch = 0;
    for (int t = 0; t < seq; ++t) {
        int p = t & 1;
        const u16* h0c = h_bf + ((size_t)(p * 2 + 0)) * LBH;
        const u16* h1c = h_bf + ((size_t)(p * 2 + 1)) * LBH;
        u16* h0n = h_bf + ((size_t)((p ^ 1) * 2 + 0)) * LBH;
        u16* h1n = h_bf + ((size_t)((p ^ 1) * 2 + 1)) * LBH;

        // ---------- phase M: out_t = sigmoid(fc_in @ Wmap.T + bmap) ----------
        if (isA) {
            int ct = wg & 31, mt = wg >> 5;       // N-tile, M-tile
            int l = mt >> 2;                       // layer for these rows
            int i = mt * 16 + c;                   // fc_in row
            int b0 = 2 * (i & 63);
            int bsel = b0 + (w >> 1);              // wave w <-> segment w
            const u16* segbase = ((w & 1) == 0)
                ? (h_bf + ((size_t)(p * 2 + l) * BATCH + bsel) * HIDN)
                : (c_bf + ((size_t)l * BATCH + bsel) * HIDN);
            const u16* ap = segbase + q * 8;
            const u16* wp = wmap + ((size_t)(16 * ct + c)) * NG + w * 1024 + q * 8;
            f32x4 acc = {0.f, 0.f, 0.f, 0.f};
#pragma unroll 4
            for (int ks = 0; ks < 32; ++ks) {
                s16x8 a = *(const s16x8*)(ap + ks * 32);
                s16x8 b = *(const s16x8*)(wp + ks * 32);
                acc = __builtin_amdgcn_mfma_f32_16x16x32_bf16(a, b, acc, 0, 0, 0);
            }
            float* sc = (float*)((char*)smem + 49152);   // 4 x 272 floats (stride 17)
#pragma unroll
            for (int r = 0; r < 4; ++r) sc[w * 272 + (q * 4 + r) * 17 + c] = acc[r];
            __syncthreads();
            {
                int row = tid >> 4, cl = tid & 15;
                float v = sc[row * 17 + cl] + sc[272 + row * 17 + cl]
                        + sc[544 + row * 17 + cl] + sc[816 + row * 17 + cl];
                int n = 16 * ct + cl;
                v = sigm(v + bmap[n]);
                int b = mt * 16 + row;
                out[((size_t)t * BATCH + b) * INPD + n] = v;
                out_bf[b * INPD + n] = f2bf(v);
            }
        }
        gbar(bar, ++epoch * NWG);

        if (t < seq - 1) {
            // ---------- phase C0 (A-class) ----------
            if (isA) {
                cellp(smem, 3072, out_bf, INPD, 16, h0c, 1024,
                      bih0, bhh0, c_f32, c_bf, h0n, wg * 4);
            }
            gbar(bar, ++epoch * NWG);
            // ---------- phase C1 (B-class) ----------
            if (!isA) {
                cellp(smem, 4096, h0n, HIDN, 32, h1c, 2048,
                      bih1, bhh1, c_f32 + LBH, c_bf + LBH, h1n, (wg - 256) * 4);
            }
            gbar(bar, ++epoch * NWG);
        } else {
            gbar(bar, ++epoch * NWG);
            gbar(bar, ++epoch * NWG);
        }
    }
}

extern "C" void kernel_launch(void* const* d_in, const int* in_sizes, int n_in,
                              void* d_out, int out_size, void* d_ws, size_t ws_size,
                              hipStream_t stream)
{
    const float* latent = (const float*)d_in[0];
    const float* Wfc  = (const float*)d_in[2];
    const float* bfc  = (const float*)d_in[3];
    const float* Wmap = (const float*)d_in[4];
    const float* bmap = (const float*)d_in[5];
    const float* Wih0 = (const float*)d_in[6];
    const float* Whh0 = (const float*)d_in[7];
    const float* bih0 = (const float*)d_in[8];
    const float* bhh0 = (const float*)d_in[9];
    const float* Wih1 = (const float*)d_in[10];
    const float* Whh1 = (const float*)d_in[11];
    const float* bih1 = (const float*)d_in[12];
    const float* bhh1 = (const float*)d_in[13];
    float* out = (float*)d_out;
    int seq = out_size / (BATCH * INPD);

    const size_t N_LAT = (size_t)BATCH * LATD;
    const size_t N_FC  = (size_t)NG * LATD;
    const size_t N_MAP = (size_t)INPD * NG;
    const size_t N_IH0 = (size_t)NG * INPD;
    const size_t N_HH  = (size_t)NG * HIDN;
    const size_t LBH   = (size_t)BATCH * HIDN;

    u16* p = (u16*)d_ws;
    u16* wbf_lat = p; p += N_LAT;
    u16* wbf_fc  = p; p += N_FC;
    u16* wbf_map = p; p += N_MAP;
    u16* wbf_ih0 = p; p += N_IH0;
    u16* wbf_hh0 = p; p += N_HH;
    u16* wbf_ih1 = p; p += N_HH;
    u16* wbf_hh1 = p; p += N_HH;
    u16* h_bf    = p; p += 4 * LBH;   // [2 parity][2 layer][B][H]
    u16* c_bf    = p; p += 2 * LBH;
    u16* out_bf  = p; p += (size_t)BATCH * INPD;
    float* c_f32 = (float*)p;
    unsigned* bar = (unsigned*)(c_f32 + 2 * LBH);

    hipMemsetAsync((void*)bar, 0, 64, stream);

    {
        struct { const float* s; u16* d; size_t n; } cv[7] = {
            {latent, wbf_lat, N_LAT}, {Wfc, wbf_fc, N_FC}, {Wmap, wbf_map, N_MAP},
            {Wih0, wbf_ih0, N_IH0}, {Whh0, wbf_hh0, N_HH},
            {Wih1, wbf_ih1, N_HH}, {Whh1, wbf_hh1, N_HH}};
        for (int qi = 0; qi < 7; ++qi) {
            int n4 = (int)(cv[qi].n / 4);
            k_cvt<<<(n4 + 255) / 256, 256, 0, stream>>>(cv[qi].s, cv[qi].d, n4);
        }
    }

    k_init<<<512, 256, 0, stream>>>(wbf_lat, wbf_fc, bfc, h_bf, c_bf, c_f32);

    k_persist<<<NWG, 256, 0, stream>>>(
        wbf_map, bmap, bih0, bhh0, bih1, bhh1,
        wbf_ih0, wbf_hh0, wbf_ih1, wbf_hh1,
        h_bf, c_bf, c_f32, out_bf, out, seq, bar);
}

// Round 5
// 18723.993 us; speedup vs baseline: 4.5154x; 2.0381x over previous
//
#include <hip/hip_runtime.h>
#include <hip/hip_bf16.h>

#define HIDN 1024
#define LATD 128
#define INPD 512
#define BATCH 128
#define NG 4096   // 4*HIDN
#define NWG 256   // merged: 256 WGs x 512 threads, 1 WG/CU

// dynamic LDS layout
#define C0_OFF 0
#define C0_RB 3072
#define C1_OFF 49152
#define C1_RB 4096
#define SC_OFF 114688
#define SMEM_BYTES 123392

typedef unsigned short u16;
typedef __attribute__((ext_vector_type(8))) short s16x8;
typedef __attribute__((ext_vector_type(4))) float f32x4;

__device__ __forceinline__ u16 f2bf(float f) {
    union { float f; unsigned u; } x;
    x.f = f;
    unsigned r = x.u + 0x7fffu + ((x.u >> 16) & 1u);
    return (u16)(r >> 16);
}
__device__ __forceinline__ float sigm(float x) {
    return 1.f / (1.f + __expf(-x));
}
__device__ __forceinline__ f32x4 shflx(f32x4 v, int m) {
    f32x4 r;
    r[0] = __shfl_xor(v[0], m);
    r[1] = __shfl_xor(v[1], m);
    r[2] = __shfl_xor(v[2], m);
    r[3] = __shfl_xor(v[3], m);
    return r;
}

// two-level device barrier: 16 groups x 16 WGs. Members release-add to group
// line; leader aggregates to root; everyone RELAXED-polls root (no L2 inval
// per poll); one agent-acquire fence at exit.
__device__ __forceinline__ void gbar(unsigned* bar, int wg, unsigned epoch) {
    __syncthreads();
    if (threadIdx.x == 0) {
        unsigned tgt = epoch * 16u;
        unsigned* grp = bar + ((wg >> 4) * 64);   // 256B apart
        unsigned* root = bar + 1024;
        __hip_atomic_fetch_add(grp, 1u, __ATOMIC_RELEASE, __HIP_MEMORY_SCOPE_AGENT);
        if ((wg & 15) == 0) {
            while (__hip_atomic_load(grp, __ATOMIC_RELAXED, __HIP_MEMORY_SCOPE_AGENT) < tgt)
                __builtin_amdgcn_s_sleep(2);
            __hip_atomic_fetch_add(root, 1u, __ATOMIC_RELEASE, __HIP_MEMORY_SCOPE_AGENT);
        }
        while (__hip_atomic_load(root, __ATOMIC_RELAXED, __HIP_MEMORY_SCOPE_AGENT) < tgt)
            __builtin_amdgcn_s_sleep(2);
        __builtin_amdgcn_fence(__ATOMIC_ACQUIRE, "agent");
    }
    __syncthreads();
}

// ---------------------------------------------------------------------------
// f32 -> bf16 conversion, 4 elements/thread
// ---------------------------------------------------------------------------
__global__ __launch_bounds__(256) void k_cvt(
    const float* __restrict__ src, u16* __restrict__ dst, int n4)
{
    int i = blockIdx.x * 256 + threadIdx.x;
    if (i < n4) {
        float4 v = ((const float4*)src)[i];
        ushort4 o;
        o.x = f2bf(v.x); o.y = f2bf(v.y); o.z = f2bf(v.z); o.w = f2bf(v.w);
        ((ushort4*)dst)[i] = o;
    }
}

// ---------------------------------------------------------------------------
// init: dh = latent @ W_fc.T + b_fc -> scatter into h[0][l][b][k], c[l][b][k]
// ---------------------------------------------------------------------------
__global__ __launch_bounds__(256) void k_init(
    const u16* __restrict__ latent, const u16* __restrict__ Wfc,
    const float* __restrict__ bfc,
    u16* __restrict__ h_bf,      // [2 parity][2 layer][B][HIDN]; writes parity 0
    u16* __restrict__ c_bf,      // [2][B][HIDN]
    float* __restrict__ c_f32)   // [2][B][HIDN]
{
    int tid = threadIdx.x, lane = tid & 63, w = tid >> 6;
    int blk = blockIdx.x;              // mt*64 + ngi
    int mt = blk >> 6, ngi = blk & 63;
    int nt = ngi * 4 + w;              // 0..255
    int arow = mt * 16 + (lane & 15);
    int ak = (lane >> 4) * 8;
    int bn = nt * 16 + (lane & 15);
    const u16* xp = latent + (size_t)arow * LATD + ak;
    const u16* wp = Wfc + (size_t)bn * LATD + ak;
    f32x4 acc = {0.f, 0.f, 0.f, 0.f};
#pragma unroll
    for (int kk = 0; kk < LATD; kk += 32) {
        s16x8 a = *(const s16x8*)(xp + kk);
        s16x8 b = *(const s16x8*)(wp + kk);
        acc = __builtin_amdgcn_mfma_f32_16x16x32_bf16(a, b, acc, 0, 0, 0);
    }
    int col = lane & 15, rbase = (lane >> 4) * 4;
    int n = nt * 16 + col;
    float bias = bfc[n];
#pragma unroll
    for (int r = 0; r < 4; ++r) {
        int m = mt * 16 + rbase + r;
        float v = acc[r] + bias;
        int ll = m >> 6;
        int bb = 2 * (m & 63) + (n >> 11);
        int k2 = n & 2047;
        size_t base = ((size_t)(ll * BATCH + bb)) << 10;
        if (k2 < 1024) {
            h_bf[base + k2] = f2bf(v);
        } else {
            int kq = k2 - 1024;
            c_f32[base + kq] = v;
            c_bf[base + kq] = f2bf(v);
        }
    }
}

// ---------------------------------------------------------------------------
// cell phase, 8-wave WG: wave w owns m-tile w (16 batch rows); WG owns 4 j
// columns x 4 gates (16 N). Weights in LDS (16 rows x RB bytes, XOR-swizzled).
// Two independent MFMA chains (accA/accB) to break dependent-MFMA latency.
// ---------------------------------------------------------------------------
__device__ __forceinline__ void cellp8(
    const char* wsl, int RB,
    const u16* __restrict__ X, int xstr, int nXks,
    const u16* __restrict__ hc, int kbH,
    const float* __restrict__ bi, const float* __restrict__ bh,
    float* __restrict__ cf, u16* __restrict__ cb, u16* __restrict__ hn,
    int j0)
{
    int tid = threadIdx.x, lane = tid & 63, w = tid >> 6;   // w: 0..7
    int c = lane & 15, q = lane >> 4;
    int sw = (c & 7) << 4;
    const char* brow = wsl + c * RB;
    const u16* ax = X + (size_t)(w * 16 + c) * xstr + q * 8;
    const u16* ah = hc + (size_t)(w * 16 + c) * HIDN + q * 8;
    f32x4 accA = {0.f, 0.f, 0.f, 0.f}, accB = {0.f, 0.f, 0.f, 0.f};
#pragma unroll 4
    for (int ks = 0; ks < nXks; ks += 2) {
        int kb0 = ks * 64 + q * 16;
        s16x8 b0 = *(const s16x8*)(brow + (kb0 ^ sw));
        s16x8 b1 = *(const s16x8*)(brow + ((kb0 + 64) ^ sw));
        s16x8 a0 = *(const s16x8*)(ax + ks * 32);
        s16x8 a1 = *(const s16x8*)(ax + ks * 32 + 32);
        accA = __builtin_amdgcn_mfma_f32_16x16x32_bf16(a0, b0, accA, 0, 0, 0);
        accB = __builtin_amdgcn_mfma_f32_16x16x32_bf16(a1, b1, accB, 0, 0, 0);
    }
#pragma unroll 4
    for (int ks = 0; ks < 32; ks += 2) {
        int kb0 = kbH + ks * 64 + q * 16;
        s16x8 b0 = *(const s16x8*)(brow + (kb0 ^ sw));
        s16x8 b1 = *(const s16x8*)(brow + ((kb0 + 64) ^ sw));
        s16x8 a0 = *(const s16x8*)(ah + ks * 32);
        s16x8 a1 = *(const s16x8*)(ah + ks * 32 + 32);
        accA = __builtin_amdgcn_mfma_f32_16x16x32_bf16(a0, b0, accA, 0, 0, 0);
        accB = __builtin_amdgcn_mfma_f32_16x16x32_bf16(a1, b1, accB, 0, 0, 0);
    }
    int n = (c >> 2) * 1024 + j0 + (c & 3);
    float bsum = bi[n] + bh[n];
    f32x4 acc;
#pragma unroll
    for (int r = 0; r < 4; ++r) acc[r] = accA[r] + accB[r] + bsum;
    f32x4 fg = shflx(acc, 4), gg = shflx(acc, 8), og = shflx(acc, 12);
    if (c < 4) {
        int j = j0 + c;
#pragma unroll
        for (int r = 0; r < 4; ++r) {
            int b = w * 16 + q * 4 + r;
            size_t idx = (size_t)b * HIDN + j;
            float cp = cf[idx];
            float iv = sigm(acc[r]), fv = sigm(fg[r]);
            float gv = tanhf(gg[r]), ov = sigm(og[r]);
            float c2 = fv * cp + iv * gv;
            float h2 = ov * tanhf(c2);
            cf[idx] = c2; cb[idx] = f2bf(c2); hn[idx] = f2bf(h2);
        }
    }
}

// ---------------------------------------------------------------------------
// persistent kernel: 256 WGs x 512 threads, 1 WG/CU, 123 KB dynamic LDS.
// All WGs participate in every phase (M, C0, C1).
// ---------------------------------------------------------------------------
__global__ __launch_bounds__(512, 1) void k_persist(
    const u16* __restrict__ wmap, const float* __restrict__ bmap,
    const float* __restrict__ bih0, const float* __restrict__ bhh0,
    const float* __restrict__ bih1, const float* __restrict__ bhh1,
    const u16* __restrict__ wih0, const u16* __restrict__ whh0,
    const u16* __restrict__ wih1, const u16* __restrict__ whh1,
    u16* __restrict__ h_bf,   // [2 parity][2 layer][B][H]
    u16* __restrict__ c_bf,   // [2 layer][B][H]
    float* __restrict__ c_f32,
    u16* __restrict__ out_bf, // [B][INPD]
    float* __restrict__ out,  // [seq][B][INPD]
    int seq, unsigned* bar)
{
    extern __shared__ char S[];
    const int wg = blockIdx.x;
    const int tid = threadIdx.x;
    const int lane = tid & 63;
    const int w = tid >> 6;            // 0..7
    const int c = lane & 15, q = lane >> 4;
    const size_t LBH = (size_t)BATCH * HIDN;

    // ---- prologue: stage both cell slices into LDS (XOR-swizzled) ----
    {
        int sub = tid & 15;
        if (tid < 256) {
            int tr = tid >> 4;                         // cell0 row 0..15
            int n = (tr >> 2) * 1024 + wg * 4 + (tr & 3);
#pragma unroll
            for (int it = 0; it < 12; ++it) {
                int kb = (sub + 16 * it) * 16;
                const u16* src = (kb < 1024) ? (wih0 + (size_t)n * 512 + (kb >> 1))
                                             : (whh0 + (size_t)n * 1024 + ((kb - 1024) >> 1));
                *(s16x8*)(S + C0_OFF + tr * C0_RB + (kb ^ ((tr & 7) << 4))) =
                    *(const s16x8*)src;
            }
        } else {
            int tr = (tid >> 4) - 16;                  // cell1 row 0..15
            int n = (tr >> 2) * 1024 + wg * 4 + (tr & 3);
#pragma unroll
            for (int it = 0; it < 16; ++it) {
                int kb = (sub + 16 * it) * 16;
                const u16* src = (kb < 2048) ? (wih1 + (size_t)n * 1024 + (kb >> 1))
                                             : (whh1 + (size_t)n * 1024 + ((kb - 2048) >> 1));
                *(s16x8*)(S + C1_OFF + tr * C1_RB + (kb ^ ((tr & 7) << 4))) =
                    *(const s16x8*)src;
            }
        }
    }
    __syncthreads();

    unsigned epoch = 0;
    for (int t = 0; t < seq; ++t) {
        int p = t & 1;
        const u16* h0c = h_bf + ((size_t)(p * 2 + 0)) * LBH;
        const u16* h1c = h_bf + ((size_t)(p * 2 + 1)) * LBH;
        u16* h0n = h_bf + ((size_t)((p ^ 1) * 2 + 0)) * LBH;
        u16* h1n = h_bf + ((size_t)((p ^ 1) * 2 + 1)) * LBH;

        // ---------- phase M: out_t = sigmoid(fc_in @ Wmap.T + bmap) ----------
        {
            int ct = wg & 31, mt = wg >> 5;       // N-tile, M-tile
            int l = mt >> 2;                       // layer for these rows
            int i_row = mt * 16 + c;               // fc_in row (load side)
            int b0 = 2 * (i_row & 63);
            int seg = w >> 1, koff = (w & 1) * 512;
            int bsel = b0 + (seg >> 1);
            const u16* segbase = (seg & 1)
                ? (c_bf + ((size_t)l * BATCH + bsel) * HIDN)
                : (h_bf + ((size_t)(p * 2 + l) * BATCH + bsel) * HIDN);
            const u16* ap = segbase + koff + q * 8;
            const u16* wp = wmap + ((size_t)(16 * ct + c)) * NG + seg * 1024 + koff + q * 8;
            f32x4 accA = {0.f, 0.f, 0.f, 0.f}, accB = {0.f, 0.f, 0.f, 0.f};
#pragma unroll 4
            for (int ks = 0; ks < 16; ks += 2) {
                s16x8 a0 = *(const s16x8*)(ap + ks * 32);
                s16x8 b0 = *(const s16x8*)(wp + ks * 32);
                s16x8 a1 = *(const s16x8*)(ap + ks * 32 + 32);
                s16x8 b1 = *(const s16x8*)(wp + ks * 32 + 32);
                accA = __builtin_amdgcn_mfma_f32_16x16x32_bf16(a0, b0, accA, 0, 0, 0);
                accB = __builtin_amdgcn_mfma_f32_16x16x32_bf16(a1, b1, accB, 0, 0, 0);
            }
            float* sc = (float*)(S + SC_OFF);      // [8][16][17]
#pragma unroll
            for (int r = 0; r < 4; ++r)
                sc[w * 272 + (q * 4 + r) * 17 + c] = accA[r] + accB[r];
            __syncthreads();
            if (tid < 256) {
                int row = tid >> 4, cl = tid & 15;
                float v = 0.f;
#pragma unroll
                for (int ww = 0; ww < 8; ++ww) v += sc[ww * 272 + row * 17 + cl];
                int n = 16 * ct + cl;
                v = sigm(v + bmap[n]);
                int b = mt * 16 + row;
                out[((size_t)t * BATCH + b) * INPD + n] = v;
                out_bf[b * INPD + n] = f2bf(v);
            }
        }
        gbar(bar, wg, ++epoch);
        if (t == seq - 1) break;

        // ---------- phase C0 ----------
        cellp8(S + C0_OFF, C0_RB, out_bf, INPD, 16, h0c, 1024,
               bih0, bhh0, c_f32, c_bf, h0n, wg * 4);
        gbar(bar, wg, ++epoch);

        // ---------- phase C1 ----------
        cellp8(S + C1_OFF, C1_RB, h0n, HIDN, 32, h1c, 2048,
               bih1, bhh1, c_f32 + LBH, c_bf + LBH, h1n, wg * 4);
        gbar(bar, wg, ++epoch);
    }
}

extern "C" void kernel_launch(void* const* d_in, const int* in_sizes, int n_in,
                              void* d_out, int out_size, void* d_ws, size_t ws_size,
                              hipStream_t stream)
{
    const float* latent = (const float*)d_in[0];
    const float* Wfc  = (const float*)d_in[2];
    const float* bfc  = (const float*)d_in[3];
    const float* Wmap = (const float*)d_in[4];
    const float* bmap = (const float*)d_in[5];
    const float* Wih0 = (const float*)d_in[6];
    const float* Whh0 = (const float*)d_in[7];
    const float* bih0 = (const float*)d_in[8];
    const float* bhh0 = (const float*)d_in[9];
    const float* Wih1 = (const float*)d_in[10];
    const float* Whh1 = (const float*)d_in[11];
    const float* bih1 = (const float*)d_in[12];
    const float* bhh1 = (const float*)d_in[13];
    float* out = (float*)d_out;
    int seq = out_size / (BATCH * INPD);

    const size_t N_LAT = (size_t)BATCH * LATD;
    const size_t N_FC  = (size_t)NG * LATD;
    const size_t N_MAP = (size_t)INPD * NG;
    const size_t N_IH0 = (size_t)NG * INPD;
    const size_t N_HH  = (size_t)NG * HIDN;
    const size_t LBH   = (size_t)BATCH * HIDN;

    u16* p = (u16*)d_ws;
    u16* wbf_lat = p; p += N_LAT;
    u16* wbf_fc  = p; p += N_FC;
    u16* wbf_map = p; p += N_MAP;
    u16* wbf_ih0 = p; p += N_IH0;
    u16* wbf_hh0 = p; p += N_HH;
    u16* wbf_ih1 = p; p += N_HH;
    u16* wbf_hh1 = p; p += N_HH;
    u16* h_bf    = p; p += 4 * LBH;   // [2 parity][2 layer][B][H]
    u16* c_bf    = p; p += 2 * LBH;
    u16* out_bf  = p; p += (size_t)BATCH * INPD;
    float* c_f32 = (float*)p;
    unsigned* bar = (unsigned*)(c_f32 + 2 * LBH);

    // opt-in to >64KB dynamic LDS (idempotent)
    hipFuncSetAttribute((const void*)k_persist,
                        hipFuncAttributeMaxDynamicSharedMemorySize, SMEM_BYTES);

    hipMemsetAsync((void*)bar, 0, 8192, stream);

    {
        struct { const float* s; u16* d; size_t n; } cv[7] = {
            {latent, wbf_lat, N_LAT}, {Wfc, wbf_fc, N_FC}, {Wmap, wbf_map, N_MAP},
            {Wih0, wbf_ih0, N_IH0}, {Whh0, wbf_hh0, N_HH},
            {Wih1, wbf_ih1, N_HH}, {Whh1, wbf_hh1, N_HH}};
        for (int qi = 0; qi < 7; ++qi) {
            int n4 = (int)(cv[qi].n / 4);
            k_cvt<<<(n4 + 255) / 256, 256, 0, stream>>>(cv[qi].s, cv[qi].d, n4);
        }
    }

    k_init<<<512, 256, 0, stream>>>(wbf_lat, wbf_fc, bfc, h_bf, c_bf, c_f32);

    k_persist<<<NWG, 512, SMEM_BYTES, stream>>>(
        wbf_map, bmap, bih0, bhh0, bih1, bhh1,
        wbf_ih0, wbf_hh0, wbf_ih1, wbf_hh1,
        h_bf, c_bf, c_f32, out_bf, out, seq, bar);
}